// Round 5
// baseline (183.419 us; speedup 1.0000x reference)
//
#include <hip/hip_runtime.h>
#include <math.h>

#define C_IN  128
#define H_IN  56
#define W_IN  56
#define HW_IN (H_IN * W_IN)          // 3136
#define N_IN  8
#define O_MID 64

// Weff layout (floats): rows of 52 per channel, slot = (di*5+dj)*2 + k
// (50 used, 2 pad so rows are 16B-aligned for b128 LDS reads)
#define WROW     52
#define WEFF_FL  (C_IN * WROW)        // 6656
#define BEFF_OFF WEFF_FL

#define NBLK  392                     // 8 * 49
#define NPROD 50                      // weff producer blocks (3200 = 50*64)

// Module-scope state. g_* data buffers are fully rewritten each iteration.
// Sync counters are MONOTONIC (never reset): block epoch = ticket/NBLK,
// and waiters compare against epoch-scaled targets. This survives warmup,
// timing loops, and rocprof replays with zero reset logic.
__device__ __align__(16) float g_weff[WEFF_FL + 4];
__device__ __align__(16) float g_G[25 * N_IN * HW_IN * 2];   // ~5.0 MB
__device__ unsigned g_ticket = 0;
__device__ unsigned g_weff_done = 0;                 // += 1 per producer
__device__ unsigned g_gdone[N_IN][49] = {};          // += 1 per (n,tile)

// ---------------- k_all: ONE dispatch, point-to-point spin sync ----------------
// R4 post-mortem: cg grid.sync() = ~50 us each on MI355X -> replaced by
// stream-K-style spins. All 392 blocks co-resident (<=170 VGPR -> 3 blk/CU,
// capacity 768), so spins always progress.
// grid dim3(8,49): linear id = n + 8*tile -> id%8 = n -> batch n pinned to one
// XCD; x[n] L2-resident; G halo neighbors (tile+-2, same n) share that L2.
__global__ __launch_bounds__(256) void k_all(const float* __restrict__ x,
                                             const float* __restrict__ Wt,
                                             const float* __restrict__ bias,
                                             const float* __restrict__ Wlin,
                                             const float* __restrict__ blin,
                                             float* __restrict__ out) {
    __shared__ float wls[WEFF_FL + 4];    // 26640 B; reused: weff partials first
    __shared__ unsigned s_ticket;

    const int tid  = threadIdx.x;
    const int n    = blockIdx.x;
    const int tile = blockIdx.y;
    const int bid  = n + 8 * tile;

    if (tid == 0)
        s_ticket = __hip_atomic_fetch_add(&g_ticket, 1u, __ATOMIC_RELAXED,
                                          __HIP_MEMORY_SCOPE_AGENT);
    __syncthreads();
    const unsigned epoch = s_ticket / NBLK;

    // ---- phase A: weff fold, 50 producer blocks (64 elements each) ----
    // Threads: el = tid&63 picks element, og = tid>>6 picks o-quarter (16 o's,
    // fully unrolled -> 16 loads in flight). LDS partial reduce across og.
    if (bid < NPROD) {
        const int el = tid & 63;
        const int og = tid >> 6;
        const int e  = bid * 64 + el;
        float a0 = 0.f, a1 = 0.f;
#pragma unroll
        for (int oo = 0; oo < 16; ++oo) {
            const int o = og * 16 + oo;
            const float wt = Wt[o * 3200 + e];
            a0 = fmaf(Wlin[o], wt, a0);
            a1 = fmaf(Wlin[64 + o], wt, a1);
        }
        float2* part = (float2*)wls;      // 256 float2 = 2 KB, overwritten later
        part[og * 64 + el] = make_float2(a0, a1);
        __syncthreads();
        if (tid < 64) {
            const float2 p0 = part[tid], p1 = part[64 + tid],
                         p2 = part[128 + tid], p3 = part[192 + tid];
            const int ee = bid * 64 + tid;
            const int c  = ee / 25;
            const int pp = ee - c * 25;
            g_weff[c * WROW + pp * 2 + 0] = p0.x + p1.x + p2.x + p3.x;
            g_weff[c * WROW + pp * 2 + 1] = p0.y + p1.y + p2.y + p3.y;
        }
        if (bid == 0 && tid >= 64 && tid < 128) {   // beff on free wave 1
            const int o = tid - 64;
            float v0 = Wlin[o] * bias[o];
            float v1 = Wlin[64 + o] * bias[o];
#pragma unroll
            for (int off = 32; off; off >>= 1) {
                v0 += __shfl_down(v0, off, 64);
                v1 += __shfl_down(v1, off, 64);
            }
            if (o == 0) {
                g_weff[BEFF_OFF + 0] = v0 + blin[0];
                g_weff[BEFF_OFF + 1] = v1 + blin[1];
            }
        }
        __syncthreads();                  // all weff stores issued+drained
        __threadfence();                  // release: visible device-wide
        if (tid == 0)
            __hip_atomic_fetch_add(&g_weff_done, 1u, __ATOMIC_RELEASE,
                                   __HIP_MEMORY_SCOPE_AGENT);
    }

    // ---- wait for weff (monotonic target; ~0 for producers, ~1.5us others) ----
    if (tid == 0) {
        const unsigned tgt = (unsigned)NPROD * (epoch + 1u);
        while (__hip_atomic_load(&g_weff_done, __ATOMIC_RELAXED,
                                 __HIP_MEMORY_SCOPE_AGENT) < tgt)
            __builtin_amdgcn_s_sleep(2);
    }
    __syncthreads();
    __threadfence();                      // acquire: invalidate L1 before g_weff reads

    // ---- stage Weff+beff to LDS ----
#pragma unroll
    for (int r = 0; r < 7; ++r) {
        const int i4 = tid + 256 * r;     // float4 index, 1665 total (incl beff)
        if (i4 < 1665)
            *(float4*)&wls[i4 * 4] = *(const float4*)&g_weff[i4 * 4];
    }
    __syncthreads();

    // ---- phase B: GEMM (R2 k_gemm verbatim — proven fastest) ----
    const int wv   = tid >> 6;
    const int lane = tid & 63;
    const int cgrp = lane >> 4;
    const int px   = lane & 15;
    const int hw   = tile * 64 + wv * 16 + px;

    {
        const float* xc = x + (size_t)n * (C_IN * HW_IN) + hw;

        float xv[32];                     // 32 independent loads in flight
#pragma unroll
        for (int s = 0; s < 32; ++s)
            xv[s] = xc[(size_t)(s * 4 + cgrp) * HW_IN];

        float acc[50];
#pragma unroll
        for (int i = 0; i < 50; ++i) acc[i] = 0.f;

#pragma unroll
        for (int s = 0; s < 32; ++s) {
            const float* wr = &wls[(s * 4 + cgrp) * WROW];
#pragma unroll
            for (int i = 0; i < 50; ++i)
                acc[i] = fmaf(xv[s], wr[i], acc[i]);
        }

#pragma unroll
        for (int i = 0; i < 50; ++i) {    // reduce across cgrp (lane bits 4,5)
            float v = acc[i];
            v += __shfl_xor(v, 16, 64);
            v += __shfl_xor(v, 32, 64);
            acc[i] = v;
        }

        // R13 lesson: keep exec-masked cgrp==0 stores — one contiguous 128B
        // segment per store instruction.
        if (cgrp == 0) {
#pragma unroll
            for (int p = 0; p < 25; ++p) {
                const size_t idx = (((size_t)p * N_IN + n) * HW_IN + hw) * 2;
                *(float2*)&g_G[idx] = make_float2(acc[p * 2 + 0], acc[p * 2 + 1]);
            }
        }
    }

    __syncthreads();                      // all G stores drained (vmcnt(0) @barrier)
    __threadfence();
    if (tid == 0)
        __hip_atomic_fetch_add(&g_gdone[n][tile], 1u, __ATOMIC_RELEASE,
                               __HIP_MEMORY_SCOPE_AGENT);

    // ---- wait for halo neighbors: tiles tile-2..tile+2, same n (<=5 flags) ----
    if (tid < 5) {
        const int s = tile - 2 + tid;
        if (s >= 0 && s < 49) {
            while (__hip_atomic_load(&g_gdone[n][s], __ATOMIC_RELAXED,
                                     __HIP_MEMORY_SCOPE_AGENT) < epoch + 1u)
                __builtin_amdgcn_s_sleep(2);
        }
    }
    __syncthreads();
    __threadfence();                      // invalidate L1 before neighbor G reads

    // ---- phase C: final stats (R2 k_final verbatim) ----
    if (tid < 128) {
        const int fpx = tid >> 1;
        const int k   = tid & 1;
        const int fhw = tile * 64 + fpx;
        const int y   = fhw / W_IN;
        const int xx0 = fhw - y * W_IN;

        const float be = wls[BEFF_OFF + k];

        float vbuf[25];
        bool  okm[25];
#pragma unroll
        for (int di = 0; di < 5; ++di) {
            const int yy = y + di - 2;
#pragma unroll
            for (int dj = 0; dj < 5; ++dj) {
                const int xx = xx0 + dj - 2;
                const int p  = di * 5 + dj;
                const bool ok = ((unsigned)yy < H_IN) && ((unsigned)xx < W_IN);
                const size_t idx = ok
                    ? ((((size_t)p * N_IN + n) * HW_IN + yy * W_IN + xx) * 2 + k)
                    : (size_t)0;
                vbuf[p] = g_G[idx];       // independent loads, all in flight
                okm[p]  = ok;
            }
        }

        float A = 0.f, X = 0.f, Y = 0.f, Cs = 0.f;
#pragma unroll
        for (int di = 0; di < 5; ++di) {
            const float fdi = (float)(di - 2);
#pragma unroll
            for (int dj = 0; dj < 5; ++dj) {
                const int p = di * 5 + dj;
                const float v = (okm[p] ? vbuf[p] : 0.f) + be;
                const float a = fabsf(v);
                A += a;
                X  = fmaf(a, (float)(dj - 2), X);
                Y  = fmaf(a, fdi, Y);
                Cs += v;
            }
        }

        const float xd = X / A, yd = Y / A;
        const float o = Cs * expf(-0.5f * sqrtf(xd * xd + yd * yd));
        out[((size_t)n * HW_IN + fhw) * 2 + k] = o;
    }
}

extern "C" void kernel_launch(void* const* d_in, const int* in_sizes, int n_in,
                              void* d_out, int out_size, void* d_ws, size_t ws_size,
                              hipStream_t stream) {
    const float* x    = (const float*)d_in[0];
    const float* Wt   = (const float*)d_in[1];
    const float* bias = (const float*)d_in[2];
    const float* Wlin = (const float*)d_in[3];
    const float* blin = (const float*)d_in[4];
    (void)d_ws; (void)ws_size;

    k_all<<<dim3(N_IN, 49), dim3(256), 0, stream>>>(x, Wt, bias, Wlin, blin,
                                                    (float*)d_out);
}